// Round 12
// baseline (210.887 us; speedup 1.0000x reference)
//
#include <hip/hip_runtime.h>

#define N_POINTS 8192
#define K_CENTERS 128
#define IFD 64
#define L1D 64
#define L2D 64
#define L3D 128

#define LD4(p) (*(const float4*)(p))

// ---------------------------------------------------------------------------
// DPP u64-max step: partner = DPP-permuted (hi,lo); keep the larger key.
// ---------------------------------------------------------------------------
template <int CTRL, int RMASK>
__device__ __forceinline__ void dpp_max_u64(unsigned& hi, unsigned& lo) {
  unsigned h2 = (unsigned)__builtin_amdgcn_update_dpp(
      (int)hi, (int)hi, CTRL, RMASK, 0xF, false);
  unsigned l2 = (unsigned)__builtin_amdgcn_update_dpp(
      (int)lo, (int)lo, CTRL, RMASK, 0xF, false);
  unsigned long long a = ((unsigned long long)hi << 32) | lo;
  unsigned long long b = ((unsigned long long)h2 << 32) | l2;
  if (b > a) { hi = h2; lo = l2; }
}

// ---------------------------------------------------------------------------
// Round-19: DRAIN-FREE FPS LOOP. r11 post-mortem: single-word publish won
// (-8.5 us) but the loop still has __syncthreads/iter, and the compiler
// emits s_waitcnt vmcnt(0) before s_barrier -> tid0's 4 global stores/iter
// (3 out_centers + 1 cidx) are drained by the WHOLE block every iteration
// (~15-25 us over 127 iters). Fix (combining two verified structures):
//  - r9's barrier-free reduce: per-iter u64 LDS slots + monotonic LDS ctr,
//    workgroup release/acquire -> only lgkmcnt waits, never vmcnt;
//  - r11's relaxed single-word publish (cidx[it] = widx, fire-and-forget);
//  - out_centers deferred: wmax_arr[it] slots retain all winners; threads
//    1..127 write all centers in one parallel pass after the loop. tid0's
//    in-loop global traffic = exactly 1 relaxed store/iter, never waited on.
// FPS math / tie-break / workers byte-identical to r11.
// ---------------------------------------------------------------------------
#define FPS_T 512
#define FPS_P (N_POINTS / FPS_T)  // 16
#define SMEM_BYTES (98304 + 1024 + 64)

#define NWORK 160
#define GT_ROWS 52               // ceil(8192/160)
#define SLICES 8
#define SLICE_PTS (N_POINTS / SLICES)  // 1024
#define TICKETS (K_CENTERS * SLICES)

__global__ void zero_ctrl(int* __restrict__ ctrl, unsigned* __restrict__ cidx) {
  if (threadIdx.x < 256) ctrl[threadIdx.x] = 0;
  if (threadIdx.x < K_CENTERS) cidx[threadIdx.x] = 0xFFFFFFFFu;
}

__global__ __launch_bounds__(FPS_T) void fused_kernel(
    const float* __restrict__ coords, float* __restrict__ out_centers,
    const float* __restrict__ features, const float* __restrict__ W1,
    const float* __restrict__ b1, const float* __restrict__ W2,
    const float* __restrict__ b2, const float* __restrict__ W3,
    const float* __restrict__ b3, float* __restrict__ GT,
    int* __restrict__ ctrl, unsigned* __restrict__ cidx,
    float* __restrict__ out_feat) {
  __shared__ __align__(16) char smem[SMEM_BYTES];
  const int tid = threadIdx.x;
  const int lane = tid & 63;
  const int wid = tid >> 6;

  int* gt_done = ctrl + 64;  // own cache line
  int* ticket = ctrl + 128;  // own cache line

  if (blockIdx.x == 0) {
    // ========== FPS (block 0): barrier-free, drain-free loop ==========
    float* clds = (float*)smem;  // [8192][3] mirror of coords
    unsigned long long* wmax_arr =
        (unsigned long long*)(smem + 98304);   // [128] per-iter slots
    int* ctr = (int*)(smem + 98304 + 1024);    // monotonic counter

    {
      const float4* __restrict__ src = (const float4*)coords;
      float4* dst = (float4*)smem;
#pragma unroll
      for (int i = 0; i < 12; i++)
        dst[tid + i * FPS_T] = src[tid + i * FPS_T];
    }
    if (tid < 128) wmax_arr[tid] = 0ull;
    if (tid == 0) *ctr = 0;

    float px[FPS_P], py[FPS_P], pz[FPS_P], mind[FPS_P];
#pragma unroll
    for (int i = 0; i < FPS_P; i++) {
      int n = tid + i * FPS_T;
      px[i] = coords[3 * n];
      py[i] = coords[3 * n + 1];
      pz[i] = coords[3 * n + 2];
      mind[i] = 1e10f;
    }

    float cx = coords[0], cy = coords[1], cz = coords[2];
    if (tid == 0)
      __hip_atomic_store(&cidx[0], 0u, __ATOMIC_RELAXED,
                         __HIP_MEMORY_SCOPE_AGENT);
    __syncthreads();  // mirror + slots + ctr init visible (only barrier)

    for (int it = 1; it < K_CENTERS; it++) {
#pragma unroll
      for (int i = 0; i < FPS_P; i++) {
        float dx = px[i] - cx, dy = py[i] - cy, dz = pz[i] - cz;
        float d2 = dx * dx + dy * dy + dz * dz;  // exact passing expr
        mind[i] = fminf(mind[i], d2);
      }
      float t8[8];
#pragma unroll
      for (int i = 0; i < 8; i++) t8[i] = fmaxf(mind[i], mind[i + 8]);
#pragma unroll
      for (int i = 0; i < 4; i++) t8[i] = fmaxf(t8[i], t8[i + 4]);
      const float bm = fmaxf(fmaxf(t8[0], t8[1]), fmaxf(t8[2], t8[3]));
      int cand[FPS_P];
#pragma unroll
      for (int i = 0; i < FPS_P; i++)
        cand[i] = (mind[i] == bm) ? (tid + i * FPS_T) : 0x7FFFFFFF;
#pragma unroll
      for (int s = 8; s > 0; s >>= 1)
#pragma unroll
        for (int i = 0; i < s; i++) cand[i] = min(cand[i], cand[i + s]);

      unsigned hi = __float_as_uint(bm);
      unsigned lo = (unsigned)(N_POINTS - 1 - cand[0]);
      dpp_max_u64<0xB1, 0xF>(hi, lo);
      dpp_max_u64<0x4E, 0xF>(hi, lo);
      dpp_max_u64<0x141, 0xF>(hi, lo);
      dpp_max_u64<0x140, 0xF>(hi, lo);
      dpp_max_u64<0x142, 0xA>(hi, lo);
      dpp_max_u64<0x143, 0xC>(hi, lo);
      if (lane == 63) {
        atomicMax(&wmax_arr[it], ((unsigned long long)hi << 32) | lo);
        __hip_atomic_fetch_add(ctr, 1, __ATOMIC_RELEASE,
                               __HIP_MEMORY_SCOPE_WORKGROUP);
      }
      const int target = it << 3;  // 8 waves contributed
      while (__hip_atomic_load(ctr, __ATOMIC_ACQUIRE,
                               __HIP_MEMORY_SCOPE_WORKGROUP) < target) {
      }
      const unsigned long long key = wmax_arr[it];  // broadcast ds_read
      const int widx = N_POINTS - 1 - (int)(key & 0xFFFFFFFFull);
      cx = clds[widx * 3];
      cy = clds[widx * 3 + 1];
      cz = clds[widx * 3 + 2];
      if (tid == 0)  // single relaxed store, fire-and-forget, never drained
        __hip_atomic_store(&cidx[it], (unsigned)widx, __ATOMIC_RELAXED,
                           __HIP_MEMORY_SCOPE_AGENT);
    }

    // deferred out_centers: slots hold every winner; one parallel pass
    __syncthreads();
    if (tid == 0) {
      out_centers[0] = coords[0];
      out_centers[1] = coords[1];
      out_centers[2] = coords[2];
    } else if (tid < K_CENTERS) {
      const unsigned long long key = wmax_arr[tid];
      const int widx = N_POINTS - 1 - (int)(key & 0xFFFFFFFFull);
      out_centers[3 * tid] = clds[widx * 3];
      out_centers[3 * tid + 1] = clds[widx * 3 + 1];
      out_centers[3 * tid + 2] = clds[widx * 3 + 2];
    }
    return;
  }

  // ======================= worker blocks 1..NWORK =======================
  float* w2s = (float*)smem;              // 16 KB (W1f for GT, then W2)
  float* w3s = (float*)(smem + 16384);    // 32 KB
  float* gt2 = (float*)(smem + 49152);    // 64*65*4 = 16640
  float* cst = (float*)(smem + 65792);    // 384 floats
  int* q = (int*)(smem + 67328);          // 1024 ints
  int* bc = (int*)(smem + 71424);         // broadcast scratch

  const int wb = blockIdx.x - 1;

  // ---- phase 1: GT (feature half of L1), W1f staged via w2s ----
  for (int s = tid; s < IFD * L1D; s += FPS_T) w2s[s] = W1[3 * L1D + s];
  __syncthreads();
  {
    const int r0 = wb * GT_ROWS;
    const int r1 = min(r0 + GT_ROWS, N_POINTS);
    const float bj = b1[lane];
    for (int r = r0 + wid; r < r1; r += 8) {
      const float* __restrict__ frow = features + (size_t)r * IFD;
      float acc = bj;
#pragma unroll 16
      for (int i = 0; i < IFD; i++)
        acc = fmaf(frow[i], w2s[i * 64 + lane], acc);
      // agent-scope atomic store: lands at coherent point (no stale L2)
      __hip_atomic_store(&GT[(size_t)r * 64 + lane], acc, __ATOMIC_RELAXED,
                         __HIP_MEMORY_SCOPE_AGENT);
    }
  }
  if (wb < 32) {  // zero out_feat (16384 floats over 32 blocks)
    __hip_atomic_store(&out_feat[wb * 512 + tid], 0.0f, __ATOMIC_RELAXED,
                       __HIP_MEMORY_SCOPE_AGENT);
  }
  __threadfence();
  __syncthreads();
  if (tid == 0) atomicAdd(gt_done, 1);

  // ---- phase 2: stage MLP weights into LDS (block-local, safe now) ----
  for (int s = tid; s < 64 * 64; s += FPS_T) w2s[s] = W2[s];
  for (int s = tid; s < 64 * 128; s += FPS_T) w3s[s] = W3[s];
  if (tid < 384) {
    float v = (tid < 192) ? W1[tid]
                          : (tid < 256 ? b2[tid - 192] : b3[tid - 256]);
    cst[tid] = v;
  }
  if (tid == 0) {
    while (__hip_atomic_load(gt_done, __ATOMIC_ACQUIRE,
                             __HIP_MEMORY_SCOPE_AGENT) < NWORK)
      __builtin_amdgcn_s_sleep(16);
  }
  __syncthreads();

  // ---- phase 3: ticket loop over (center, slice) ----
  for (;;) {
    if (tid == 0) bc[0] = atomicAdd(ticket, 1);
    __syncthreads();
    const int t = bc[0];
    if (t >= TICKETS) break;
    const int k = t >> 3;       // SLICES = 8
    const int slice = t & 7;

    if (tid == 0) {
      unsigned v;
      while ((v = __hip_atomic_load(&cidx[k], __ATOMIC_RELAXED,
                                    __HIP_MEMORY_SCOPE_AGENT)) == 0xFFFFFFFFu)
        __builtin_amdgcn_s_sleep(8);
      bc[1] = (int)v;  // winner index; coords come from read-only input
      bc[4] = 0;       // qc
    }
    __syncthreads();
    const int cw = bc[1];
    const float ckx = coords[3 * cw];
    const float cky = coords[3 * cw + 1];
    const float ckz = coords[3 * cw + 2];

    // ball scan of this slice -> LDS queue
    const int nb = slice * SLICE_PTS;
#pragma unroll
    for (int it2 = 0; it2 < SLICE_PTS / FPS_T; it2++) {
      const int n = nb + it2 * FPS_T + tid;
      const float ddx = coords[3 * n] - ckx;
      const float ddy = coords[3 * n + 1] - cky;
      const float ddz = coords[3 * n + 2] - ckz;
      const float d2 = ddx * ddx + ddy * ddy + ddz * ddz;
      if (sqrtf(d2) < 1.0f) {  // match reference: norm(rel) < RADIUS
        int p = atomicAdd(&bc[4], 1);
        q[p] = n;
      }
    }
    __syncthreads();
    const int M = bc[4];

    if (M > 0) {
      const int nc = (M + 63) >> 6;
      float vmax[16];
#pragma unroll
      for (int t2 = 0; t2 < 16; t2++) vmax[t2] = 0.0f;

      for (int c = 0; c < nc; c++) {
        const int m0 = c << 6;
        // stage 64 GT rows (8 per wave), coalesced
#pragma unroll
        for (int jr = 0; jr < 8; jr++) {
          const int row = (wid << 3) + jr;
          int mm = m0 + row;
          if (mm >= M) mm = M - 1;  // duplicate pad: max-safe
          int nrow = q[mm];
          nrow = __builtin_amdgcn_readfirstlane(nrow);
          gt2[row * 65 + lane] = GT[(size_t)nrow * 64 + lane];
        }
        __syncthreads();

        // L1+L2: point p = lane; channels (wid*8 .. +8)
        int m = m0 + lane;
        if (m >= M) m = M - 1;
        const int n = q[m];
        const float dx = coords[3 * n] - ckx;
        const float dy = coords[3 * n + 1] - cky;
        const float dz = coords[3 * n + 2] - ckz;

        float acc[8];
#pragma unroll
        for (int t2 = 0; t2 < 8; t2++) acc[t2] = cst[192 + (wid << 3) + t2];
#pragma unroll 4
        for (int i = 0; i < 64; i++) {
          const float g = gt2[lane * 65 + i];
          const float e = fmaxf(
              fmaf(dz, cst[128 + i],
                   fmaf(dy, cst[64 + i], fmaf(dx, cst[i], g))),
              0.0f);
          const float4 wa = LD4(w2s + i * 64 + (wid << 3));
          const float4 wb4 = LD4(w2s + i * 64 + (wid << 3) + 4);
          acc[0] = fmaf(e, wa.x, acc[0]);
          acc[1] = fmaf(e, wa.y, acc[1]);
          acc[2] = fmaf(e, wa.z, acc[2]);
          acc[3] = fmaf(e, wa.w, acc[3]);
          acc[4] = fmaf(e, wb4.x, acc[4]);
          acc[5] = fmaf(e, wb4.y, acc[5]);
          acc[6] = fmaf(e, wb4.z, acc[6]);
          acc[7] = fmaf(e, wb4.w, acc[7]);
        }
        __syncthreads();  // gt2 reads done before h2 overwrite
#pragma unroll
        for (int t2 = 0; t2 < 8; t2++)
          gt2[lane * 65 + (wid << 3) + t2] = fmaxf(acc[t2], 0.0f);
        __syncthreads();

        // L3: point p = lane; out channels (wid*16 .. +16)
        float a3[16];
#pragma unroll
        for (int t2 = 0; t2 < 16; t2++) a3[t2] = cst[256 + (wid << 4) + t2];
#pragma unroll 2
        for (int i = 0; i < 64; i++) {
          const float hv = gt2[lane * 65 + i];
          const float* __restrict__ w3r = w3s + i * L3D + (wid << 4);
          const float4 wa = LD4(w3r);
          const float4 wb4 = LD4(w3r + 4);
          const float4 wc = LD4(w3r + 8);
          const float4 wd = LD4(w3r + 12);
          a3[0] = fmaf(hv, wa.x, a3[0]);
          a3[1] = fmaf(hv, wa.y, a3[1]);
          a3[2] = fmaf(hv, wa.z, a3[2]);
          a3[3] = fmaf(hv, wa.w, a3[3]);
          a3[4] = fmaf(hv, wb4.x, a3[4]);
          a3[5] = fmaf(hv, wb4.y, a3[5]);
          a3[6] = fmaf(hv, wb4.z, a3[6]);
          a3[7] = fmaf(hv, wb4.w, a3[7]);
          a3[8] = fmaf(hv, wc.x, a3[8]);
          a3[9] = fmaf(hv, wc.y, a3[9]);
          a3[10] = fmaf(hv, wc.z, a3[10]);
          a3[11] = fmaf(hv, wc.w, a3[11]);
          a3[12] = fmaf(hv, wd.x, a3[12]);
          a3[13] = fmaf(hv, wd.y, a3[13]);
          a3[14] = fmaf(hv, wd.z, a3[14]);
          a3[15] = fmaf(hv, wd.w, a3[15]);
        }
#pragma unroll
        for (int t2 = 0; t2 < 16; t2++)
          vmax[t2] = fmaxf(vmax[t2], fmaxf(a3[t2], 0.0f));
        __syncthreads();  // L3 reads done before next staging
      }

      // flush this (center, slice)
#pragma unroll
      for (int t2 = 0; t2 < 16; t2++) {
        float v = vmax[t2];
#pragma unroll
        for (int off = 32; off >= 1; off >>= 1)
          v = fmaxf(v, __shfl_xor(v, off, 64));
        if (lane == 0)
          atomicMax((unsigned*)&out_feat[k * L3D + (wid << 4) + t2],
                    __float_as_uint(v));
      }
    }
  }
}

// ---------------------------------------------------------------------------
extern "C" void kernel_launch(void* const* d_in, const int* in_sizes, int n_in,
                              void* d_out, int out_size, void* d_ws,
                              size_t ws_size, hipStream_t stream) {
  const float* coords = (const float*)d_in[0];    // [8192,3]
  const float* features = (const float*)d_in[1];  // [8192,64]
  const float* W1 = (const float*)d_in[2];        // [67,64]
  const float* b1 = (const float*)d_in[3];        // [64]
  const float* W2 = (const float*)d_in[4];        // [64,64]
  const float* b2 = (const float*)d_in[5];        // [64]
  const float* W3 = (const float*)d_in[6];        // [64,128]
  const float* b3 = (const float*)d_in[7];        // [128]

  float* out = (float*)d_out;
  float* centers = out;                   // [128*3]
  float* out_feat = out + K_CENTERS * 3;  // [128*128]

  char* ws = (char*)d_ws;
  float* GT = (float*)ws;  // 2 MB, [8192][64]
  int* ctrl = (int*)(ws + (size_t)N_POINTS * L1D * 4);  // 1 KB (padded vars)
  unsigned* cidx = (unsigned*)(ws + (size_t)N_POINTS * L1D * 4 + 1024);

  zero_ctrl<<<1, 384, 0, stream>>>(ctrl, cidx);
  fused_kernel<<<1 + NWORK, FPS_T, 0, stream>>>(coords, centers, features,
                                                W1, b1, W2, b2, W3, b3, GT,
                                                ctrl, cidx, out_feat);
}

// Round 13
// 204.023 us; speedup vs baseline: 1.0336x; 1.0336x over previous
//
#include <hip/hip_runtime.h>

#define N_POINTS 8192
#define K_CENTERS 128
#define IFD 64
#define L1D 64
#define L2D 64
#define L3D 128

#define LD4(p) (*(const float4*)(p))

typedef float v2f __attribute__((ext_vector_type(2)));

// ---------------------------------------------------------------------------
// DPP u64-max step: partner = DPP-permuted (hi,lo); keep the larger key.
// ---------------------------------------------------------------------------
template <int CTRL, int RMASK>
__device__ __forceinline__ void dpp_max_u64(unsigned& hi, unsigned& lo) {
  unsigned h2 = (unsigned)__builtin_amdgcn_update_dpp(
      (int)hi, (int)hi, CTRL, RMASK, 0xF, false);
  unsigned l2 = (unsigned)__builtin_amdgcn_update_dpp(
      (int)lo, (int)lo, CTRL, RMASK, 0xF, false);
  unsigned long long a = ((unsigned long long)hi << 32) | lo;
  unsigned long long b = ((unsigned long long)h2 << 32) | l2;
  if (b > a) { hi = h2; lo = l2; }
}

// ---------------------------------------------------------------------------
// Round-20: PACKED-FP32 FPS UPDATE. r12 post-mortem: sync mechanics
// exonerated 3x (barrier / barrier-free / drain-free all equal); fps loop
// issue is dominated by the 112-instr scalar fmin block. CDNA4 has full-
// rate packed FP32 (v_pk_add/mul/fma_f32, VOP3P); LLVM selects them for
// <2 x float>. px/py/pz/mind stored as 8 float2/thread: update = 3 pk_sub
// + 1 pk_mul + 2 pk_fma + 2 v_min per point-PAIR (64 instr vs 112, -43%).
// Exactness: elementwise IEEE fp32, same expression shape -> same
// contraction per element -> same winners. Value tree / index tie-break
// (compile-time extracts) / DPP chain / publish / workers byte-identical
// to r12. If codegen declines to pack: neutral, not wrong.
// ---------------------------------------------------------------------------
#define FPS_T 512
#define FPS_P (N_POINTS / FPS_T)  // 16
#define SMEM_BYTES (98304 + 1024 + 64)

#define NWORK 160
#define GT_ROWS 52               // ceil(8192/160)
#define SLICES 8
#define SLICE_PTS (N_POINTS / SLICES)  // 1024
#define TICKETS (K_CENTERS * SLICES)

#define MIND(i) (mind2[(i) >> 1][(i) & 1])

__global__ void zero_ctrl(int* __restrict__ ctrl, unsigned* __restrict__ cidx) {
  if (threadIdx.x < 256) ctrl[threadIdx.x] = 0;
  if (threadIdx.x < K_CENTERS) cidx[threadIdx.x] = 0xFFFFFFFFu;
}

__global__ __launch_bounds__(FPS_T) void fused_kernel(
    const float* __restrict__ coords, float* __restrict__ out_centers,
    const float* __restrict__ features, const float* __restrict__ W1,
    const float* __restrict__ b1, const float* __restrict__ W2,
    const float* __restrict__ b2, const float* __restrict__ W3,
    const float* __restrict__ b3, float* __restrict__ GT,
    int* __restrict__ ctrl, unsigned* __restrict__ cidx,
    float* __restrict__ out_feat) {
  __shared__ __align__(16) char smem[SMEM_BYTES];
  const int tid = threadIdx.x;
  const int lane = tid & 63;
  const int wid = tid >> 6;

  int* gt_done = ctrl + 64;  // own cache line
  int* ticket = ctrl + 128;  // own cache line

  if (blockIdx.x == 0) {
    // ========== FPS (block 0): barrier-free, drain-free, packed ==========
    float* clds = (float*)smem;  // [8192][3] mirror of coords
    unsigned long long* wmax_arr =
        (unsigned long long*)(smem + 98304);   // [128] per-iter slots
    int* ctr = (int*)(smem + 98304 + 1024);    // monotonic counter

    {
      const float4* __restrict__ src = (const float4*)coords;
      float4* dst = (float4*)smem;
#pragma unroll
      for (int i = 0; i < 12; i++)
        dst[tid + i * FPS_T] = src[tid + i * FPS_T];
    }
    if (tid < 128) wmax_arr[tid] = 0ull;
    if (tid == 0) *ctr = 0;

    // pair layout: pair j holds points i=2j (lane 0) and i=2j+1 (lane 1);
    // point i is global index tid + i*FPS_T (same mapping as r12).
    v2f px2[8], py2[8], pz2[8], mind2[8];
#pragma unroll
    for (int j = 0; j < 8; j++) {
      const int n0 = tid + (2 * j) * FPS_T;
      const int n1 = tid + (2 * j + 1) * FPS_T;
      px2[j] = (v2f){coords[3 * n0], coords[3 * n1]};
      py2[j] = (v2f){coords[3 * n0 + 1], coords[3 * n1 + 1]};
      pz2[j] = (v2f){coords[3 * n0 + 2], coords[3 * n1 + 2]};
      mind2[j] = (v2f){1e10f, 1e10f};
    }

    float cx = coords[0], cy = coords[1], cz = coords[2];
    if (tid == 0)
      __hip_atomic_store(&cidx[0], 0u, __ATOMIC_RELAXED,
                         __HIP_MEMORY_SCOPE_AGENT);
    __syncthreads();  // mirror + slots + ctr init visible (only barrier)

    for (int it = 1; it < K_CENTERS; it++) {
      const v2f cx2 = {cx, cx}, cy2 = {cy, cy}, cz2 = {cz, cz};
#pragma unroll
      for (int j = 0; j < 8; j++) {
        v2f dx = px2[j] - cx2, dy = py2[j] - cy2, dz = pz2[j] - cz2;
        v2f d2 = dx * dx + dy * dy + dz * dz;  // same expr shape as scalar
        mind2[j] = __builtin_elementwise_min(mind2[j], d2);
      }
      // value: depth-4 fmax tree (identical structure, static extracts)
      float t8[8];
#pragma unroll
      for (int i = 0; i < 8; i++) t8[i] = fmaxf(MIND(i), MIND(i + 8));
#pragma unroll
      for (int i = 0; i < 4; i++) t8[i] = fmaxf(t8[i], t8[i + 4]);
      const float bm = fmaxf(fmaxf(t8[0], t8[1]), fmaxf(t8[2], t8[3]));
      // index: 16 parallel cndmask + depth-4 min tree (first match = min)
      int cand[FPS_P];
#pragma unroll
      for (int i = 0; i < FPS_P; i++)
        cand[i] = (MIND(i) == bm) ? (tid + i * FPS_T) : 0x7FFFFFFF;
#pragma unroll
      for (int s = 8; s > 0; s >>= 1)
#pragma unroll
        for (int i = 0; i < s; i++) cand[i] = min(cand[i], cand[i + s]);

      unsigned hi = __float_as_uint(bm);
      unsigned lo = (unsigned)(N_POINTS - 1 - cand[0]);
      dpp_max_u64<0xB1, 0xF>(hi, lo);
      dpp_max_u64<0x4E, 0xF>(hi, lo);
      dpp_max_u64<0x141, 0xF>(hi, lo);
      dpp_max_u64<0x140, 0xF>(hi, lo);
      dpp_max_u64<0x142, 0xA>(hi, lo);
      dpp_max_u64<0x143, 0xC>(hi, lo);
      if (lane == 63) {
        atomicMax(&wmax_arr[it], ((unsigned long long)hi << 32) | lo);
        __hip_atomic_fetch_add(ctr, 1, __ATOMIC_RELEASE,
                               __HIP_MEMORY_SCOPE_WORKGROUP);
      }
      const int target = it << 3;  // 8 waves contributed
      while (__hip_atomic_load(ctr, __ATOMIC_ACQUIRE,
                               __HIP_MEMORY_SCOPE_WORKGROUP) < target) {
      }
      const unsigned long long key = wmax_arr[it];  // broadcast ds_read
      const int widx = N_POINTS - 1 - (int)(key & 0xFFFFFFFFull);
      cx = clds[widx * 3];
      cy = clds[widx * 3 + 1];
      cz = clds[widx * 3 + 2];
      if (tid == 0)  // single relaxed store, fire-and-forget, never drained
        __hip_atomic_store(&cidx[it], (unsigned)widx, __ATOMIC_RELAXED,
                           __HIP_MEMORY_SCOPE_AGENT);
    }

    // deferred out_centers: slots hold every winner; one parallel pass
    __syncthreads();
    if (tid == 0) {
      out_centers[0] = coords[0];
      out_centers[1] = coords[1];
      out_centers[2] = coords[2];
    } else if (tid < K_CENTERS) {
      const unsigned long long key = wmax_arr[tid];
      const int widx = N_POINTS - 1 - (int)(key & 0xFFFFFFFFull);
      out_centers[3 * tid] = clds[widx * 3];
      out_centers[3 * tid + 1] = clds[widx * 3 + 1];
      out_centers[3 * tid + 2] = clds[widx * 3 + 2];
    }
    return;
  }

  // ======================= worker blocks 1..NWORK =======================
  float* w2s = (float*)smem;              // 16 KB (W1f for GT, then W2)
  float* w3s = (float*)(smem + 16384);    // 32 KB
  float* gt2 = (float*)(smem + 49152);    // 64*65*4 = 16640
  float* cst = (float*)(smem + 65792);    // 384 floats
  int* q = (int*)(smem + 67328);          // 1024 ints
  int* bc = (int*)(smem + 71424);         // broadcast scratch

  const int wb = blockIdx.x - 1;

  // ---- phase 1: GT (feature half of L1), W1f staged via w2s ----
  for (int s = tid; s < IFD * L1D; s += FPS_T) w2s[s] = W1[3 * L1D + s];
  __syncthreads();
  {
    const int r0 = wb * GT_ROWS;
    const int r1 = min(r0 + GT_ROWS, N_POINTS);
    const float bj = b1[lane];
    for (int r = r0 + wid; r < r1; r += 8) {
      const float* __restrict__ frow = features + (size_t)r * IFD;
      float acc = bj;
#pragma unroll 16
      for (int i = 0; i < IFD; i++)
        acc = fmaf(frow[i], w2s[i * 64 + lane], acc);
      // agent-scope atomic store: lands at coherent point (no stale L2)
      __hip_atomic_store(&GT[(size_t)r * 64 + lane], acc, __ATOMIC_RELAXED,
                         __HIP_MEMORY_SCOPE_AGENT);
    }
  }
  if (wb < 32) {  // zero out_feat (16384 floats over 32 blocks)
    __hip_atomic_store(&out_feat[wb * 512 + tid], 0.0f, __ATOMIC_RELAXED,
                       __HIP_MEMORY_SCOPE_AGENT);
  }
  __threadfence();
  __syncthreads();
  if (tid == 0) atomicAdd(gt_done, 1);

  // ---- phase 2: stage MLP weights into LDS (block-local, safe now) ----
  for (int s = tid; s < 64 * 64; s += FPS_T) w2s[s] = W2[s];
  for (int s = tid; s < 64 * 128; s += FPS_T) w3s[s] = W3[s];
  if (tid < 384) {
    float v = (tid < 192) ? W1[tid]
                          : (tid < 256 ? b2[tid - 192] : b3[tid - 256]);
    cst[tid] = v;
  }
  if (tid == 0) {
    while (__hip_atomic_load(gt_done, __ATOMIC_ACQUIRE,
                             __HIP_MEMORY_SCOPE_AGENT) < NWORK)
      __builtin_amdgcn_s_sleep(16);
  }
  __syncthreads();

  // ---- phase 3: ticket loop over (center, slice) ----
  for (;;) {
    if (tid == 0) bc[0] = atomicAdd(ticket, 1);
    __syncthreads();
    const int t = bc[0];
    if (t >= TICKETS) break;
    const int k = t >> 3;       // SLICES = 8
    const int slice = t & 7;

    if (tid == 0) {
      unsigned v;
      while ((v = __hip_atomic_load(&cidx[k], __ATOMIC_RELAXED,
                                    __HIP_MEMORY_SCOPE_AGENT)) == 0xFFFFFFFFu)
        __builtin_amdgcn_s_sleep(8);
      bc[1] = (int)v;  // winner index; coords come from read-only input
      bc[4] = 0;       // qc
    }
    __syncthreads();
    const int cw = bc[1];
    const float ckx = coords[3 * cw];
    const float cky = coords[3 * cw + 1];
    const float ckz = coords[3 * cw + 2];

    // ball scan of this slice -> LDS queue
    const int nb = slice * SLICE_PTS;
#pragma unroll
    for (int it2 = 0; it2 < SLICE_PTS / FPS_T; it2++) {
      const int n = nb + it2 * FPS_T + tid;
      const float ddx = coords[3 * n] - ckx;
      const float ddy = coords[3 * n + 1] - cky;
      const float ddz = coords[3 * n + 2] - ckz;
      const float d2 = ddx * ddx + ddy * ddy + ddz * ddz;
      if (sqrtf(d2) < 1.0f) {  // match reference: norm(rel) < RADIUS
        int p = atomicAdd(&bc[4], 1);
        q[p] = n;
      }
    }
    __syncthreads();
    const int M = bc[4];

    if (M > 0) {
      const int nc = (M + 63) >> 6;
      float vmax[16];
#pragma unroll
      for (int t2 = 0; t2 < 16; t2++) vmax[t2] = 0.0f;

      for (int c = 0; c < nc; c++) {
        const int m0 = c << 6;
        // stage 64 GT rows (8 per wave), coalesced
#pragma unroll
        for (int jr = 0; jr < 8; jr++) {
          const int row = (wid << 3) + jr;
          int mm = m0 + row;
          if (mm >= M) mm = M - 1;  // duplicate pad: max-safe
          int nrow = q[mm];
          nrow = __builtin_amdgcn_readfirstlane(nrow);
          gt2[row * 65 + lane] = GT[(size_t)nrow * 64 + lane];
        }
        __syncthreads();

        // L1+L2: point p = lane; channels (wid*8 .. +8)
        int m = m0 + lane;
        if (m >= M) m = M - 1;
        const int n = q[m];
        const float dx = coords[3 * n] - ckx;
        const float dy = coords[3 * n + 1] - cky;
        const float dz = coords[3 * n + 2] - ckz;

        float acc[8];
#pragma unroll
        for (int t2 = 0; t2 < 8; t2++) acc[t2] = cst[192 + (wid << 3) + t2];
#pragma unroll 4
        for (int i = 0; i < 64; i++) {
          const float g = gt2[lane * 65 + i];
          const float e = fmaxf(
              fmaf(dz, cst[128 + i],
                   fmaf(dy, cst[64 + i], fmaf(dx, cst[i], g))),
              0.0f);
          const float4 wa = LD4(w2s + i * 64 + (wid << 3));
          const float4 wb4 = LD4(w2s + i * 64 + (wid << 3) + 4);
          acc[0] = fmaf(e, wa.x, acc[0]);
          acc[1] = fmaf(e, wa.y, acc[1]);
          acc[2] = fmaf(e, wa.z, acc[2]);
          acc[3] = fmaf(e, wa.w, acc[3]);
          acc[4] = fmaf(e, wb4.x, acc[4]);
          acc[5] = fmaf(e, wb4.y, acc[5]);
          acc[6] = fmaf(e, wb4.z, acc[6]);
          acc[7] = fmaf(e, wb4.w, acc[7]);
        }
        __syncthreads();  // gt2 reads done before h2 overwrite
#pragma unroll
        for (int t2 = 0; t2 < 8; t2++)
          gt2[lane * 65 + (wid << 3) + t2] = fmaxf(acc[t2], 0.0f);
        __syncthreads();

        // L3: point p = lane; out channels (wid*16 .. +16)
        float a3[16];
#pragma unroll
        for (int t2 = 0; t2 < 16; t2++) a3[t2] = cst[256 + (wid << 4) + t2];
#pragma unroll 2
        for (int i = 0; i < 64; i++) {
          const float hv = gt2[lane * 65 + i];
          const float* __restrict__ w3r = w3s + i * L3D + (wid << 4);
          const float4 wa = LD4(w3r);
          const float4 wb4 = LD4(w3r + 4);
          const float4 wc = LD4(w3r + 8);
          const float4 wd = LD4(w3r + 12);
          a3[0] = fmaf(hv, wa.x, a3[0]);
          a3[1] = fmaf(hv, wa.y, a3[1]);
          a3[2] = fmaf(hv, wa.z, a3[2]);
          a3[3] = fmaf(hv, wa.w, a3[3]);
          a3[4] = fmaf(hv, wb4.x, a3[4]);
          a3[5] = fmaf(hv, wb4.y, a3[5]);
          a3[6] = fmaf(hv, wb4.z, a3[6]);
          a3[7] = fmaf(hv, wb4.w, a3[7]);
          a3[8] = fmaf(hv, wc.x, a3[8]);
          a3[9] = fmaf(hv, wc.y, a3[9]);
          a3[10] = fmaf(hv, wc.z, a3[10]);
          a3[11] = fmaf(hv, wc.w, a3[11]);
          a3[12] = fmaf(hv, wd.x, a3[12]);
          a3[13] = fmaf(hv, wd.y, a3[13]);
          a3[14] = fmaf(hv, wd.z, a3[14]);
          a3[15] = fmaf(hv, wd.w, a3[15]);
        }
#pragma unroll
        for (int t2 = 0; t2 < 16; t2++)
          vmax[t2] = fmaxf(vmax[t2], fmaxf(a3[t2], 0.0f));
        __syncthreads();  // L3 reads done before next staging
      }

      // flush this (center, slice)
#pragma unroll
      for (int t2 = 0; t2 < 16; t2++) {
        float v = vmax[t2];
#pragma unroll
        for (int off = 32; off >= 1; off >>= 1)
          v = fmaxf(v, __shfl_xor(v, off, 64));
        if (lane == 0)
          atomicMax((unsigned*)&out_feat[k * L3D + (wid << 4) + t2],
                    __float_as_uint(v));
      }
    }
  }
}

// ---------------------------------------------------------------------------
extern "C" void kernel_launch(void* const* d_in, const int* in_sizes, int n_in,
                              void* d_out, int out_size, void* d_ws,
                              size_t ws_size, hipStream_t stream) {
  const float* coords = (const float*)d_in[0];    // [8192,3]
  const float* features = (const float*)d_in[1];  // [8192,64]
  const float* W1 = (const float*)d_in[2];        // [67,64]
  const float* b1 = (const float*)d_in[3];        // [64]
  const float* W2 = (const float*)d_in[4];        // [64,64]
  const float* b2 = (const float*)d_in[5];        // [64]
  const float* W3 = (const float*)d_in[6];        // [64,128]
  const float* b3 = (const float*)d_in[7];        // [128]

  float* out = (float*)d_out;
  float* centers = out;                   // [128*3]
  float* out_feat = out + K_CENTERS * 3;  // [128*128]

  char* ws = (char*)d_ws;
  float* GT = (float*)ws;  // 2 MB, [8192][64]
  int* ctrl = (int*)(ws + (size_t)N_POINTS * L1D * 4);  // 1 KB (padded vars)
  unsigned* cidx = (unsigned*)(ws + (size_t)N_POINTS * L1D * 4 + 1024);

  zero_ctrl<<<1, 384, 0, stream>>>(ctrl, cidx);
  fused_kernel<<<1 + NWORK, FPS_T, 0, stream>>>(coords, centers, features,
                                                W1, b1, W2, b2, W3, b3, GT,
                                                ctrl, cidx, out_feat);
}

// Round 14
// 203.683 us; speedup vs baseline: 1.0354x; 1.0017x over previous
//
#include <hip/hip_runtime.h>

#define N_POINTS 8192
#define K_CENTERS 128
#define IFD 64
#define L1D 64
#define L2D 64
#define L3D 128

#define LD4(p) (*(const float4*)(p))

typedef float v2f __attribute__((ext_vector_type(2)));

// ---------------------------------------------------------------------------
// DPP u64-max step: partner = DPP-permuted (hi,lo); keep the larger key.
// ---------------------------------------------------------------------------
template <int CTRL, int RMASK>
__device__ __forceinline__ void dpp_max_u64(unsigned& hi, unsigned& lo) {
  unsigned h2 = (unsigned)__builtin_amdgcn_update_dpp(
      (int)hi, (int)hi, CTRL, RMASK, 0xF, false);
  unsigned l2 = (unsigned)__builtin_amdgcn_update_dpp(
      (int)lo, (int)lo, CTRL, RMASK, 0xF, false);
  unsigned long long a = ((unsigned long long)hi << 32) | lo;
  unsigned long long b = ((unsigned long long)h2 << 32) | l2;
  if (b > a) { hi = h2; lo = l2; }
}

// ---------------------------------------------------------------------------
// Round-21: TAIL + STARTUP TRIM. r13 model validated: kernel 143 = fps 134
// (latency-chain floor, 10 variants) + tail ~9-12 (last center / 8 slices
// x 4 chunks) + startup. Changes (constants only, math identical):
//  - SLICES 8 -> 16 (SLICE_PTS=512 = one full-block scan pass): last
//    center splits 16 ways -> ~2 chunks/ticket -> tail ~5 us. Chunk pad
//    waste unchanged (16*ceil(106/64) == 8*ceil(212/64)).
//  - NWORK 160 -> 254 (255 blocks <= 256 CUs, 1 block/CU): GT phase 52 ->
//    33 rows/block; more blocks to pounce on late tickets.
// Pre-commit: if kernel >= 141 us, declare structural limit.
// ---------------------------------------------------------------------------
#define FPS_T 512
#define FPS_P (N_POINTS / FPS_T)  // 16
#define SMEM_BYTES (98304 + 1024 + 64)

#define NWORK 254
#define GT_ROWS 33               // ceil(8192/254)
#define SLICES 16
#define SLICE_PTS (N_POINTS / SLICES)  // 512
#define TICKETS (K_CENTERS * SLICES)

#define MIND(i) (mind2[(i) >> 1][(i) & 1])

__global__ void zero_ctrl(int* __restrict__ ctrl, unsigned* __restrict__ cidx) {
  if (threadIdx.x < 256) ctrl[threadIdx.x] = 0;
  if (threadIdx.x < K_CENTERS) cidx[threadIdx.x] = 0xFFFFFFFFu;
}

__global__ __launch_bounds__(FPS_T) void fused_kernel(
    const float* __restrict__ coords, float* __restrict__ out_centers,
    const float* __restrict__ features, const float* __restrict__ W1,
    const float* __restrict__ b1, const float* __restrict__ W2,
    const float* __restrict__ b2, const float* __restrict__ W3,
    const float* __restrict__ b3, float* __restrict__ GT,
    int* __restrict__ ctrl, unsigned* __restrict__ cidx,
    float* __restrict__ out_feat) {
  __shared__ __align__(16) char smem[SMEM_BYTES];
  const int tid = threadIdx.x;
  const int lane = tid & 63;
  const int wid = tid >> 6;

  int* gt_done = ctrl + 64;  // own cache line
  int* ticket = ctrl + 128;  // own cache line

  if (blockIdx.x == 0) {
    // ========== FPS (block 0): barrier-free, drain-free, packed ==========
    float* clds = (float*)smem;  // [8192][3] mirror of coords
    unsigned long long* wmax_arr =
        (unsigned long long*)(smem + 98304);   // [128] per-iter slots
    int* ctr = (int*)(smem + 98304 + 1024);    // monotonic counter

    {
      const float4* __restrict__ src = (const float4*)coords;
      float4* dst = (float4*)smem;
#pragma unroll
      for (int i = 0; i < 12; i++)
        dst[tid + i * FPS_T] = src[tid + i * FPS_T];
    }
    if (tid < 128) wmax_arr[tid] = 0ull;
    if (tid == 0) *ctr = 0;

    // pair layout: pair j holds points i=2j (lane 0) and i=2j+1 (lane 1);
    // point i is global index tid + i*FPS_T (same mapping as r12).
    v2f px2[8], py2[8], pz2[8], mind2[8];
#pragma unroll
    for (int j = 0; j < 8; j++) {
      const int n0 = tid + (2 * j) * FPS_T;
      const int n1 = tid + (2 * j + 1) * FPS_T;
      px2[j] = (v2f){coords[3 * n0], coords[3 * n1]};
      py2[j] = (v2f){coords[3 * n0 + 1], coords[3 * n1 + 1]};
      pz2[j] = (v2f){coords[3 * n0 + 2], coords[3 * n1 + 2]};
      mind2[j] = (v2f){1e10f, 1e10f};
    }

    float cx = coords[0], cy = coords[1], cz = coords[2];
    if (tid == 0)
      __hip_atomic_store(&cidx[0], 0u, __ATOMIC_RELAXED,
                         __HIP_MEMORY_SCOPE_AGENT);
    __syncthreads();  // mirror + slots + ctr init visible (only barrier)

    for (int it = 1; it < K_CENTERS; it++) {
      const v2f cx2 = {cx, cx}, cy2 = {cy, cy}, cz2 = {cz, cz};
#pragma unroll
      for (int j = 0; j < 8; j++) {
        v2f dx = px2[j] - cx2, dy = py2[j] - cy2, dz = pz2[j] - cz2;
        v2f d2 = dx * dx + dy * dy + dz * dz;  // same expr shape as scalar
        mind2[j] = __builtin_elementwise_min(mind2[j], d2);
      }
      // value: depth-4 fmax tree (identical structure, static extracts)
      float t8[8];
#pragma unroll
      for (int i = 0; i < 8; i++) t8[i] = fmaxf(MIND(i), MIND(i + 8));
#pragma unroll
      for (int i = 0; i < 4; i++) t8[i] = fmaxf(t8[i], t8[i + 4]);
      const float bm = fmaxf(fmaxf(t8[0], t8[1]), fmaxf(t8[2], t8[3]));
      // index: 16 parallel cndmask + depth-4 min tree (first match = min)
      int cand[FPS_P];
#pragma unroll
      for (int i = 0; i < FPS_P; i++)
        cand[i] = (MIND(i) == bm) ? (tid + i * FPS_T) : 0x7FFFFFFF;
#pragma unroll
      for (int s = 8; s > 0; s >>= 1)
#pragma unroll
        for (int i = 0; i < s; i++) cand[i] = min(cand[i], cand[i + s]);

      unsigned hi = __float_as_uint(bm);
      unsigned lo = (unsigned)(N_POINTS - 1 - cand[0]);
      dpp_max_u64<0xB1, 0xF>(hi, lo);
      dpp_max_u64<0x4E, 0xF>(hi, lo);
      dpp_max_u64<0x141, 0xF>(hi, lo);
      dpp_max_u64<0x140, 0xF>(hi, lo);
      dpp_max_u64<0x142, 0xA>(hi, lo);
      dpp_max_u64<0x143, 0xC>(hi, lo);
      if (lane == 63) {
        atomicMax(&wmax_arr[it], ((unsigned long long)hi << 32) | lo);
        __hip_atomic_fetch_add(ctr, 1, __ATOMIC_RELEASE,
                               __HIP_MEMORY_SCOPE_WORKGROUP);
      }
      const int target = it << 3;  // 8 waves contributed
      while (__hip_atomic_load(ctr, __ATOMIC_ACQUIRE,
                               __HIP_MEMORY_SCOPE_WORKGROUP) < target) {
      }
      const unsigned long long key = wmax_arr[it];  // broadcast ds_read
      const int widx = N_POINTS - 1 - (int)(key & 0xFFFFFFFFull);
      cx = clds[widx * 3];
      cy = clds[widx * 3 + 1];
      cz = clds[widx * 3 + 2];
      if (tid == 0)  // single relaxed store, fire-and-forget, never drained
        __hip_atomic_store(&cidx[it], (unsigned)widx, __ATOMIC_RELAXED,
                           __HIP_MEMORY_SCOPE_AGENT);
    }

    // deferred out_centers: slots hold every winner; one parallel pass
    __syncthreads();
    if (tid == 0) {
      out_centers[0] = coords[0];
      out_centers[1] = coords[1];
      out_centers[2] = coords[2];
    } else if (tid < K_CENTERS) {
      const unsigned long long key = wmax_arr[tid];
      const int widx = N_POINTS - 1 - (int)(key & 0xFFFFFFFFull);
      out_centers[3 * tid] = clds[widx * 3];
      out_centers[3 * tid + 1] = clds[widx * 3 + 1];
      out_centers[3 * tid + 2] = clds[widx * 3 + 2];
    }
    return;
  }

  // ======================= worker blocks 1..NWORK =======================
  float* w2s = (float*)smem;              // 16 KB (W1f for GT, then W2)
  float* w3s = (float*)(smem + 16384);    // 32 KB
  float* gt2 = (float*)(smem + 49152);    // 64*65*4 = 16640
  float* cst = (float*)(smem + 65792);    // 384 floats
  int* q = (int*)(smem + 67328);          // 1024 ints
  int* bc = (int*)(smem + 71424);         // broadcast scratch

  const int wb = blockIdx.x - 1;

  // ---- phase 1: GT (feature half of L1), W1f staged via w2s ----
  for (int s = tid; s < IFD * L1D; s += FPS_T) w2s[s] = W1[3 * L1D + s];
  __syncthreads();
  {
    const int r0 = wb * GT_ROWS;
    const int r1 = min(r0 + GT_ROWS, N_POINTS);
    const float bj = b1[lane];
    for (int r = r0 + wid; r < r1; r += 8) {
      const float* __restrict__ frow = features + (size_t)r * IFD;
      float acc = bj;
#pragma unroll 16
      for (int i = 0; i < IFD; i++)
        acc = fmaf(frow[i], w2s[i * 64 + lane], acc);
      // agent-scope atomic store: lands at coherent point (no stale L2)
      __hip_atomic_store(&GT[(size_t)r * 64 + lane], acc, __ATOMIC_RELAXED,
                         __HIP_MEMORY_SCOPE_AGENT);
    }
  }
  if (wb < 32) {  // zero out_feat (16384 floats over 32 blocks)
    __hip_atomic_store(&out_feat[wb * 512 + tid], 0.0f, __ATOMIC_RELAXED,
                       __HIP_MEMORY_SCOPE_AGENT);
  }
  __threadfence();
  __syncthreads();
  if (tid == 0) atomicAdd(gt_done, 1);

  // ---- phase 2: stage MLP weights into LDS (block-local, safe now) ----
  for (int s = tid; s < 64 * 64; s += FPS_T) w2s[s] = W2[s];
  for (int s = tid; s < 64 * 128; s += FPS_T) w3s[s] = W3[s];
  if (tid < 384) {
    float v = (tid < 192) ? W1[tid]
                          : (tid < 256 ? b2[tid - 192] : b3[tid - 256]);
    cst[tid] = v;
  }
  if (tid == 0) {
    while (__hip_atomic_load(gt_done, __ATOMIC_ACQUIRE,
                             __HIP_MEMORY_SCOPE_AGENT) < NWORK)
      __builtin_amdgcn_s_sleep(16);
  }
  __syncthreads();

  // ---- phase 3: ticket loop over (center, slice) ----
  for (;;) {
    if (tid == 0) bc[0] = atomicAdd(ticket, 1);
    __syncthreads();
    const int t = bc[0];
    if (t >= TICKETS) break;
    const int k = t >> 4;        // SLICES = 16
    const int slice = t & 15;

    if (tid == 0) {
      unsigned v;
      while ((v = __hip_atomic_load(&cidx[k], __ATOMIC_RELAXED,
                                    __HIP_MEMORY_SCOPE_AGENT)) == 0xFFFFFFFFu)
        __builtin_amdgcn_s_sleep(8);
      bc[1] = (int)v;  // winner index; coords come from read-only input
      bc[4] = 0;       // qc
    }
    __syncthreads();
    const int cw = bc[1];
    const float ckx = coords[3 * cw];
    const float cky = coords[3 * cw + 1];
    const float ckz = coords[3 * cw + 2];

    // ball scan of this slice -> LDS queue (one full-block pass)
    {
      const int n = slice * SLICE_PTS + tid;
      const float ddx = coords[3 * n] - ckx;
      const float ddy = coords[3 * n + 1] - cky;
      const float ddz = coords[3 * n + 2] - ckz;
      const float d2 = ddx * ddx + ddy * ddy + ddz * ddz;
      if (sqrtf(d2) < 1.0f) {  // match reference: norm(rel) < RADIUS
        int p = atomicAdd(&bc[4], 1);
        q[p] = n;
      }
    }
    __syncthreads();
    const int M = bc[4];

    if (M > 0) {
      const int nc = (M + 63) >> 6;
      float vmax[16];
#pragma unroll
      for (int t2 = 0; t2 < 16; t2++) vmax[t2] = 0.0f;

      for (int c = 0; c < nc; c++) {
        const int m0 = c << 6;
        // stage 64 GT rows (8 per wave), coalesced
#pragma unroll
        for (int jr = 0; jr < 8; jr++) {
          const int row = (wid << 3) + jr;
          int mm = m0 + row;
          if (mm >= M) mm = M - 1;  // duplicate pad: max-safe
          int nrow = q[mm];
          nrow = __builtin_amdgcn_readfirstlane(nrow);
          gt2[row * 65 + lane] = GT[(size_t)nrow * 64 + lane];
        }
        __syncthreads();

        // L1+L2: point p = lane; channels (wid*8 .. +8)
        int m = m0 + lane;
        if (m >= M) m = M - 1;
        const int n = q[m];
        const float dx = coords[3 * n] - ckx;
        const float dy = coords[3 * n + 1] - cky;
        const float dz = coords[3 * n + 2] - ckz;

        float acc[8];
#pragma unroll
        for (int t2 = 0; t2 < 8; t2++) acc[t2] = cst[192 + (wid << 3) + t2];
#pragma unroll 4
        for (int i = 0; i < 64; i++) {
          const float g = gt2[lane * 65 + i];
          const float e = fmaxf(
              fmaf(dz, cst[128 + i],
                   fmaf(dy, cst[64 + i], fmaf(dx, cst[i], g))),
              0.0f);
          const float4 wa = LD4(w2s + i * 64 + (wid << 3));
          const float4 wb4 = LD4(w2s + i * 64 + (wid << 3) + 4);
          acc[0] = fmaf(e, wa.x, acc[0]);
          acc[1] = fmaf(e, wa.y, acc[1]);
          acc[2] = fmaf(e, wa.z, acc[2]);
          acc[3] = fmaf(e, wa.w, acc[3]);
          acc[4] = fmaf(e, wb4.x, acc[4]);
          acc[5] = fmaf(e, wb4.y, acc[5]);
          acc[6] = fmaf(e, wb4.z, acc[6]);
          acc[7] = fmaf(e, wb4.w, acc[7]);
        }
        __syncthreads();  // gt2 reads done before h2 overwrite
#pragma unroll
        for (int t2 = 0; t2 < 8; t2++)
          gt2[lane * 65 + (wid << 3) + t2] = fmaxf(acc[t2], 0.0f);
        __syncthreads();

        // L3: point p = lane; out channels (wid*16 .. +16)
        float a3[16];
#pragma unroll
        for (int t2 = 0; t2 < 16; t2++) a3[t2] = cst[256 + (wid << 4) + t2];
#pragma unroll 2
        for (int i = 0; i < 64; i++) {
          const float hv = gt2[lane * 65 + i];
          const float* __restrict__ w3r = w3s + i * L3D + (wid << 4);
          const float4 wa = LD4(w3r);
          const float4 wb4 = LD4(w3r + 4);
          const float4 wc = LD4(w3r + 8);
          const float4 wd = LD4(w3r + 12);
          a3[0] = fmaf(hv, wa.x, a3[0]);
          a3[1] = fmaf(hv, wa.y, a3[1]);
          a3[2] = fmaf(hv, wa.z, a3[2]);
          a3[3] = fmaf(hv, wa.w, a3[3]);
          a3[4] = fmaf(hv, wb4.x, a3[4]);
          a3[5] = fmaf(hv, wb4.y, a3[5]);
          a3[6] = fmaf(hv, wb4.z, a3[6]);
          a3[7] = fmaf(hv, wb4.w, a3[7]);
          a3[8] = fmaf(hv, wc.x, a3[8]);
          a3[9] = fmaf(hv, wc.y, a3[9]);
          a3[10] = fmaf(hv, wc.z, a3[10]);
          a3[11] = fmaf(hv, wc.w, a3[11]);
          a3[12] = fmaf(hv, wd.x, a3[12]);
          a3[13] = fmaf(hv, wd.y, a3[13]);
          a3[14] = fmaf(hv, wd.z, a3[14]);
          a3[15] = fmaf(hv, wd.w, a3[15]);
        }
#pragma unroll
        for (int t2 = 0; t2 < 16; t2++)
          vmax[t2] = fmaxf(vmax[t2], fmaxf(a3[t2], 0.0f));
        __syncthreads();  // L3 reads done before next staging
      }

      // flush this (center, slice)
#pragma unroll
      for (int t2 = 0; t2 < 16; t2++) {
        float v = vmax[t2];
#pragma unroll
        for (int off = 32; off >= 1; off >>= 1)
          v = fmaxf(v, __shfl_xor(v, off, 64));
        if (lane == 0)
          atomicMax((unsigned*)&out_feat[k * L3D + (wid << 4) + t2],
                    __float_as_uint(v));
      }
    }
  }
}

// ---------------------------------------------------------------------------
extern "C" void kernel_launch(void* const* d_in, const int* in_sizes, int n_in,
                              void* d_out, int out_size, void* d_ws,
                              size_t ws_size, hipStream_t stream) {
  const float* coords = (const float*)d_in[0];    // [8192,3]
  const float* features = (const float*)d_in[1];  // [8192,64]
  const float* W1 = (const float*)d_in[2];        // [67,64]
  const float* b1 = (const float*)d_in[3];        // [64]
  const float* W2 = (const float*)d_in[4];        // [64,64]
  const float* b2 = (const float*)d_in[5];        // [64]
  const float* W3 = (const float*)d_in[6];        // [64,128]
  const float* b3 = (const float*)d_in[7];        // [128]

  float* out = (float*)d_out;
  float* centers = out;                   // [128*3]
  float* out_feat = out + K_CENTERS * 3;  // [128*128]

  char* ws = (char*)d_ws;
  float* GT = (float*)ws;  // 2 MB, [8192][64]
  int* ctrl = (int*)(ws + (size_t)N_POINTS * L1D * 4);  // 1 KB (padded vars)
  unsigned* cidx = (unsigned*)(ws + (size_t)N_POINTS * L1D * 4 + 1024);

  zero_ctrl<<<1, 384, 0, stream>>>(ctrl, cidx);
  fused_kernel<<<1 + NWORK, FPS_T, 0, stream>>>(coords, centers, features,
                                                W1, b1, W2, b2, W3, b3, GT,
                                                ctrl, cidx, out_feat);
}